// Round 25
// baseline (53.810 us; speedup 1.0000x reference)
//
#include <hip/hip_runtime.h>
#include <hip/hip_bf16.h>

#define BB 4
#define LL 512
#define NTYPES 20
#define HH 6
#define DKK 10
#define DMM 60
#define PROW 516        // residue-major padded row: 3 regions x 172
#define NWROW 516       // W row padding (slot = (j%3)*172 + j/3)
#define KROW 12         // padded LDS row: 48 B -> b128-aligned

// ---------------- helpers ----------------
__device__ __forceinline__ float softplus_fast(float x) {
    return fmaxf(x, 0.0f) + __logf(1.0f + __expf(-fabsf(x)));
}

// ---------------- kernel A: feat -> q, kR, vR + W; 8 positions per block ----------------
__global__ __launch_bounds__(256) void ishp_qkv(
        const float* __restrict__ ev, const float* __restrict__ embed_w,
        const float* __restrict__ qw, const float* __restrict__ qb,
        const float* __restrict__ kw, const float* __restrict__ kb,
        const float* __restrict__ vw, const float* __restrict__ vb,
        const float* __restrict__ aw, const float* __restrict__ gw,
        float* __restrict__ q, float* __restrict__ kR, float* __restrict__ vR,
        float* __restrict__ Wbuf)
{
    int blk = blockIdx.x;            // 256 blocks; positions blk*8 .. blk*8+7
    int b = blk >> 6;
    int l0 = (blk & 63) * 8;
    __shared__ float sFeat[8][61];
    __shared__ float sv8[8][DMM];
    __shared__ int   sTyp[8];
    int t = threadIdx.x;

    if (t < 8) {
        int l = l0 + t;
        float t1 = ev[(b * (LL + 1) + l) * 2 + 0];
        float t0 = (l > 0) ? ev[(b * (LL + 1) + l - 1) * 2 + 0] : 0.0f;
        sFeat[t][0] = t1 - t0;
        sTyp[t] = (int)ev[(b * (LL + 1) + l) * 2 + 1];
    }
    __syncthreads();
    #pragma unroll
    for (int u = 0; u < 2; ++u) {
        int idx = u * 256 + t;
        if (idx < 472) {
            int l = idx / 59, c = idx - (idx / 59) * 59;
            sFeat[l][1 + c] = embed_w[c * NTYPES + sTyp[l]];
        }
    }
    __syncthreads();

    if (t < 180) {
        int which = t / DMM;
        int m = t - which * DMM;
        const float* w  = which == 0 ? qw : which == 1 ? kw : vw;
        const float* bs = which == 0 ? qb : which == 1 ? kb : vb;
        float bias = bs[m];
        float wr[DMM];
        #pragma unroll
        for (int c = 0; c < DMM; ++c) wr[c] = w[m * DMM + c];
        int h = m / DKK, d = m - h * DKK;
        #pragma unroll
        for (int s = 0; s < 8; ++s) {
            float acc = bias;
            #pragma unroll
            for (int c = 0; c < DMM; ++c) acc += sFeat[s][c] * wr[c];
            int l = l0 + s;
            size_t off = ((size_t)(b * HH + h) * LL + l) * DKK + d;
            if (which == 0)      q [off] = acc;
            else if (which == 1) kR[off] = acc;
            else { vR[off] = acc; sv8[s][m] = acc; }
        }
    }
    __syncthreads();

    if (t < 180) {
        int kk = t % 10;
        int u = t / 10;            // 0..17
        int h  = u % 3;
        int cc = (u / 3) % 3;
        int mat = u / 9;           // 0 = alpha, 1 = gamma
        const float* w = mat ? gw : aw;
        float wr[DKK];
        #pragma unroll
        for (int d = 0; d < DKK; ++d) wr[d] = w[kk * 30 + cc * 10 + d];
        size_t rowbase = ((size_t)((((mat * 3 + cc) * 4 + b) * 3 + h) * 10 + kk)) * NWROW;
        #pragma unroll
        for (int s = 0; s < 8; ++s) {
            float acc = 0.0f;
            #pragma unroll
            for (int d = 0; d < DKK; ++d) acc += wr[d] * sv8[s][(h + 3 * mat) * DKK + d];
            int l = l0 + s;
            int slot = (l % 3) * 172 + l / 3;
            Wbuf[rowbase + slot] = acc;
        }
    }
}

// ---------------- kernel B: attention; single-pass, 4 rows/wave, raw-e store ----------------
// pbuf holds RAW e (bf16); invS[bh*512+i] side-buffer; ag applies normalization.
// vmupre bit-identical (PV already accumulated raw-e then scaled).
__global__ __launch_bounds__(256) void ishp_attn(const float* __restrict__ q,
                                                 const float* __restrict__ kR,
                                                 const float* __restrict__ vR,
                                                 __hip_bfloat16* __restrict__ pbuf,
                                                 float* __restrict__ invSbuf,
                                                 float* __restrict__ vmupre)
{
    __shared__ float sK[LL * KROW];   // [j][12], 24576 B
    __shared__ float sV[LL * KROW];
    int bh = blockIdx.x >> 5;
    int rg = blockIdx.x & 31;
    int tid = threadIdx.x;
    int lane = tid & 63;
    int wv = tid >> 6;

    const float2* k2 = reinterpret_cast<const float2*>(kR + (size_t)bh * DKK * LL);
    const float2* v2 = reinterpret_cast<const float2*>(vR + (size_t)bh * DKK * LL);
    #pragma unroll
    for (int u = 0; u < 10; ++u) {
        int idx = u * 256 + tid;        // 0..2559
        int l = idx / 5, dp = idx - (idx / 5) * 5;
        float2 kv = k2[idx];
        sK[l * KROW + 2 * dp]     = kv.x;
        sK[l * KROW + 2 * dp + 1] = kv.y;
        float2 vv = v2[idx];
        sV[l * KROW + 2 * dp]     = vv.x;
        sV[l * KROW + 2 * dp + 1] = vv.y;
    }
    __syncthreads();

    const float scale = 0.31622776601683794f; // 1/sqrt(10)

    // 4 rows: pairs P0=rg*8+wv, P1=P0+4 -> rows {511-P0, P0, 511-P1, P1}
    int P0 = rg * 8 + wv;
    int rows[4];
    rows[0] = 511 - P0; rows[1] = P0; rows[2] = 507 - P0; rows[3] = P0 + 4;

    float qr[4][DKK];
    int nch[4];
    #pragma unroll
    for (int r = 0; r < 4; ++r) {
        #pragma unroll
        for (int d = 0; d < DKK; ++d) qr[r][d] = q[((size_t)bh * LL + rows[r]) * DKK + d];
        nch[r] = (rows[r] >> 6) + 1;
    }
    float S[4] = {0.f, 0.f, 0.f, 0.f};
    float acc[4][DKK];
    #pragma unroll
    for (int r = 0; r < 4; ++r)
        #pragma unroll
        for (int d = 0; d < DKK; ++d) acc[r][d] = 0.0f;

    int nmax = nch[0];
    for (int c = 0; c < nmax; ++c) {
        int j = c * 64 + lane;
        int slot = (j % 3) * 172 + j / 3;
        const float* kr = &sK[j * KROW];
        float4 k0 = *reinterpret_cast<const float4*>(kr);
        float4 k1 = *reinterpret_cast<const float4*>(kr + 4);
        float2 kv2 = *reinterpret_cast<const float2*>(kr + 8);
        const float* vr = &sV[j * KROW];
        float4 v0 = *reinterpret_cast<const float4*>(vr);
        float4 v1 = *reinterpret_cast<const float4*>(vr + 4);
        float2 vv2 = *reinterpret_cast<const float2*>(vr + 8);
        #pragma unroll
        for (int r = 0; r < 4; ++r) {
            if (c < nch[r]) {
                float dt = qr[r][0] * k0.x; dt += qr[r][1] * k0.y; dt += qr[r][2] * k0.z; dt += qr[r][3] * k0.w;
                dt += qr[r][4] * k1.x; dt += qr[r][5] * k1.y; dt += qr[r][6] * k1.z; dt += qr[r][7] * k1.w;
                dt += qr[r][8] * kv2.x; dt += qr[r][9] * kv2.y;
                float e = 0.0f;
                if (j <= rows[r]) {
                    e = __expf(dt * scale);
                    pbuf[(size_t)(bh * LL + rows[r]) * PROW + slot] = __float2bfloat16(e);
                }
                S[r] += e;
                acc[r][0] += e * v0.x; acc[r][1] += e * v0.y; acc[r][2] += e * v0.z; acc[r][3] += e * v0.w;
                acc[r][4] += e * v1.x; acc[r][5] += e * v1.y; acc[r][6] += e * v1.z; acc[r][7] += e * v1.w;
                acc[r][8] += e * vv2.x; acc[r][9] += e * vv2.y;
            }
        }
    }
    #pragma unroll
    for (int r = 0; r < 4; ++r)
        #pragma unroll
        for (int off = 32; off >= 1; off >>= 1) S[r] += __shfl_xor(S[r], off, 64);
    float inv[4];
    #pragma unroll
    for (int r = 0; r < 4; ++r) inv[r] = 1.0f / S[r];

    #pragma unroll
    for (int r = 0; r < 4; ++r)
        #pragma unroll
        for (int d = 0; d < DKK; ++d) {
            float a = acc[r][d];
            #pragma unroll
            for (int off = 32; off >= 1; off >>= 1) a += __shfl_xor(a, off, 64);
            acc[r][d] = a;
        }
    if (lane == 0) {
        #pragma unroll
        for (int r = 0; r < 4; ++r) {
            invSbuf[(size_t)bh * LL + rows[r]] = inv[r];
            #pragma unroll
            for (int d = 0; d < DKK; ++d)
                vmupre[((size_t)bh * LL + rows[r]) * DKK + d] = acc[r][d] * inv[r];
        }
    }
}

// ---------------- kernel C: v_alpha / v_gamma (+fused v_mu); applies invS ----------------
__global__ __launch_bounds__(256) void ishp_ag(const __hip_bfloat16* __restrict__ pbuf,
                                               const float* __restrict__ invSbuf,
                                               const float* __restrict__ Wbuf,
                                               const float* __restrict__ ab,
                                               const float* __restrict__ gb,
                                               const float* __restrict__ vmupre,
                                               const float* __restrict__ muw,
                                               const float* __restrict__ mub,
                                               float* __restrict__ out_mu,
                                               float* __restrict__ outA,
                                               float* __restrict__ outG)
{
    __shared__ float sA[2560];
    __shared__ float sG[2560];
    int tid = threadIdx.x;
    int pos = blockIdx.x * 256 + tid;
    int b  = pos >> 18;
    int i2 = (pos >> 9) & 511;
    int j2 = pos & 511;

    float ra[DKK], rg[DKK];
    if (j2 > i2) {
        #pragma unroll
        for (int kk = 0; kk < DKK; ++kk) { ra[kk] = 0.0f; rg[kk] = 0.0f; }
    } else {
        #pragma unroll
        for (int kk = 0; kk < DKK; ++kk) { ra[kk] = ab[kk]; rg[kk] = gb[kk]; }
        #pragma unroll
        for (int cc = 0; cc < 3; ++cc) {
            int u = 3 * j2 + cc;
            int sel = u >> 9;
            int j = u & 511;
            int hi = 3 * i2 + sel;
            int h = hi >> 9;
            int i = hi & 511;
            int jq = j / 3;
            int r = j - 3 * jq;
            int slot = r * 172 + jq;
            float pa = 0.0f, pg = 0.0f;
            if (j <= i) {
                float ea = __bfloat162float(pbuf[(size_t)((b * HH + h) * LL + i) * PROW + slot]);
                float eg = __bfloat162float(pbuf[(size_t)((b * HH + h + 3) * LL + i) * PROW + slot]);
                pa = ea * invSbuf[(size_t)(b * HH + h) * LL + i];
                pg = eg * invSbuf[(size_t)(b * HH + h + 3) * LL + i];
            }
            const float* Wa = Wbuf + ((size_t)(((0 + cc) * 4 + b) * 3 + h) * 10) * NWROW + slot;
            const float* Wg = Wbuf + ((size_t)(((3 + cc) * 4 + b) * 3 + h) * 10) * NWROW + slot;
            #pragma unroll
            for (int kk = 0; kk < DKK; ++kk) {
                ra[kk] += pa * Wa[kk * NWROW];
                rg[kk] += pg * Wg[kk * NWROW];
            }
        }
        #pragma unroll
        for (int kk = 0; kk < DKK; ++kk) {
            ra[kk] = softplus_fast(ra[kk]);
            rg[kk] = softplus_fast(10.0f * rg[kk]) * 0.1f;
        }
    }
    #pragma unroll
    for (int kk = 0; kk < DKK; ++kk) { sA[tid * 10 + kk] = ra[kk]; sG[tid * 10 + kk] = rg[kk]; }
    __syncthreads();

    size_t base = (size_t)blockIdx.x * 2560;
    #pragma unroll
    for (int it = 0; it < 3; ++it) {
        int idx = it * 1024 + tid * 4;
        if (idx < 2560) {
            *reinterpret_cast<float4*>(outA + base + idx) = *reinterpret_cast<const float4*>(&sA[idx]);
            *reinterpret_cast<float4*>(outG + base + idx) = *reinterpret_cast<const float4*>(&sG[idx]);
        }
    }

    if (blockIdx.x < 8) {
        int mpos = blockIdx.x * 256 + tid;    // b*L + l
        int mb = mpos >> 9, ml = mpos & 511;
        float y[DKK];
        #pragma unroll
        for (int kk = 0; kk < DKK; ++kk) y[kk] = mub[kk];
        for (int c = 0; c < DMM; ++c) {
            int h = c / DKK, d = c - h * DKK;
            float xc = vmupre[((mb * HH + h) * LL + ml) * DKK + d];
            #pragma unroll
            for (int kk = 0; kk < DKK; ++kk) y[kk] += xc * muw[kk * DMM + c];
        }
        #pragma unroll
        for (int kk = 0; kk < DKK; ++kk)
            out_mu[(size_t)mpos * DKK + kk] = 1.0f / (1.0f + __expf(-y[kk]));
    }
}

// ---------------- launch ----------------
extern "C" void kernel_launch(void* const* d_in, const int* in_sizes, int n_in,
                              void* d_out, int out_size, void* d_ws, size_t ws_size,
                              hipStream_t stream) {
    const void *ev = 0, *emb = 0, *muw = 0;
    const void *w3[3] = {0, 0, 0}, *b3[3] = {0, 0, 0};
    const void *w300[2] = {0, 0};
    const void *b10[3] = {0, 0, 0};
    int n3 = 0, nb3 = 0, n300 = 0, n10 = 0;
    for (int i = 0; i < n_in; ++i) {
        int s = in_sizes[i];
        if      (s == 4104) ev  = d_in[i];
        else if (s == 1180) emb = d_in[i];
        else if (s == 600)  muw = d_in[i];
        else if (s == 3600) { if (n3  < 3) w3[n3++]   = d_in[i]; }
        else if (s == 60)   { if (nb3 < 3) b3[nb3++]  = d_in[i]; }
        else if (s == 300)  { if (n300< 2) w300[n300++]=d_in[i]; }
        else if (s == 10)   { if (n10 < 3) b10[n10++] = d_in[i]; }
    }

    float* ws = (float*)d_ws;
    float* q = ws;
    float* kR = q + 122880;
    float* vR = kR + 122880;
    float* vmupre = vR + 122880;
    float* Wbuf = vmupre + 122880;
    float* invSbuf = Wbuf + 371520;                      // 12288 floats
    __hip_bfloat16* pbuf = (__hip_bfloat16*)(invSbuf + 12288);

    float* out = (float*)d_out;
    float* out_mu = out;
    float* out_a  = out + 20480;
    float* out_g  = out + 20480 + 10485760;

    ishp_qkv<<<(BB * LL) / 8, 256, 0, stream>>>((const float*)ev, (const float*)emb,
        (const float*)w3[0], (const float*)b3[0],
        (const float*)w3[1], (const float*)b3[1],
        (const float*)w3[2], (const float*)b3[2],
        (const float*)w300[0], (const float*)w300[1],
        q, kR, vR, Wbuf);
    ishp_attn<<<BB * HH * 32, 256, 0, stream>>>(q, kR, vR, pbuf, invSbuf, vmupre);
    ishp_ag<<<(BB * LL * LL) / 256, 256, 0, stream>>>(pbuf, invSbuf, Wbuf,
        (const float*)b10[0], (const float*)b10[1], vmupre,
        (const float*)muw, (const float*)b10[2], out_mu, out_a, out_g);
}